// Round 1
// baseline (9203.322 us; speedup 1.0000x reference)
//
#include <hip/hip_runtime.h>

// Problem constants (match reference)
#define Wd 256
#define Hd 256
#define Nn 65536   // H*W
#define Cc 64
#define Vv 4
#define Bb 2
#define BVn 8
#define EPSf 1e-8f

// ---------------- small matrix helpers (device) ----------------

__device__ inline void mat4_mul(const float* A, const float* B, float* C) {
#pragma unroll
  for (int i = 0; i < 4; i++)
#pragma unroll
    for (int j = 0; j < 4; j++) {
      float s = 0.f;
#pragma unroll
      for (int k = 0; k < 4; k++) s += A[i * 4 + k] * B[k * 4 + j];
      C[i * 4 + j] = s;
    }
}

// Standard adjugate-based 4x4 inverse (layout-agnostic: works row-major).
__device__ inline void mat4_inv(const float* m, float* invOut) {
  float inv[16];
  inv[0] = m[5]*m[10]*m[15] - m[5]*m[11]*m[14] - m[9]*m[6]*m[15] +
           m[9]*m[7]*m[14] + m[13]*m[6]*m[11] - m[13]*m[7]*m[10];
  inv[4] = -m[4]*m[10]*m[15] + m[4]*m[11]*m[14] + m[8]*m[6]*m[15] -
           m[8]*m[7]*m[14] - m[12]*m[6]*m[11] + m[12]*m[7]*m[10];
  inv[8] = m[4]*m[9]*m[15] - m[4]*m[11]*m[13] - m[8]*m[5]*m[15] +
           m[8]*m[7]*m[13] + m[12]*m[5]*m[11] - m[12]*m[7]*m[9];
  inv[12] = -m[4]*m[9]*m[14] + m[4]*m[10]*m[13] + m[8]*m[5]*m[14] -
            m[8]*m[6]*m[13] - m[12]*m[5]*m[10] + m[12]*m[6]*m[9];
  inv[1] = -m[1]*m[10]*m[15] + m[1]*m[11]*m[14] + m[9]*m[2]*m[15] -
           m[9]*m[3]*m[14] - m[13]*m[2]*m[11] + m[13]*m[3]*m[10];
  inv[5] = m[0]*m[10]*m[15] - m[0]*m[11]*m[14] - m[8]*m[2]*m[15] +
           m[8]*m[3]*m[14] + m[12]*m[2]*m[11] - m[12]*m[3]*m[10];
  inv[9] = -m[0]*m[9]*m[15] + m[0]*m[11]*m[13] + m[8]*m[1]*m[15] -
           m[8]*m[3]*m[13] - m[12]*m[1]*m[11] + m[12]*m[3]*m[9];
  inv[13] = m[0]*m[9]*m[14] - m[0]*m[10]*m[13] - m[8]*m[1]*m[14] +
            m[8]*m[2]*m[13] + m[12]*m[1]*m[10] - m[12]*m[2]*m[9];
  inv[2] = m[1]*m[6]*m[15] - m[1]*m[7]*m[14] - m[5]*m[2]*m[15] +
           m[5]*m[3]*m[14] + m[13]*m[2]*m[7] - m[13]*m[3]*m[6];
  inv[6] = -m[0]*m[6]*m[15] + m[0]*m[7]*m[14] + m[4]*m[2]*m[15] -
           m[4]*m[3]*m[14] - m[12]*m[2]*m[7] + m[12]*m[3]*m[6];
  inv[10] = m[0]*m[5]*m[15] - m[0]*m[7]*m[13] - m[4]*m[1]*m[15] +
            m[4]*m[3]*m[13] + m[12]*m[1]*m[7] - m[12]*m[3]*m[5];
  inv[14] = -m[0]*m[5]*m[14] + m[0]*m[6]*m[13] + m[4]*m[1]*m[14] -
            m[4]*m[2]*m[13] - m[12]*m[1]*m[6] + m[12]*m[2]*m[5];
  inv[3] = -m[1]*m[6]*m[11] + m[1]*m[7]*m[10] + m[5]*m[2]*m[11] -
           m[5]*m[3]*m[10] - m[9]*m[2]*m[7] + m[9]*m[3]*m[6];
  inv[7] = m[0]*m[6]*m[11] - m[0]*m[7]*m[10] - m[4]*m[2]*m[11] +
           m[4]*m[3]*m[10] + m[8]*m[2]*m[7] - m[8]*m[3]*m[6];
  inv[11] = -m[0]*m[5]*m[11] + m[0]*m[7]*m[9] + m[4]*m[1]*m[11] -
            m[4]*m[3]*m[9] - m[8]*m[1]*m[7] + m[8]*m[3]*m[5];
  inv[15] = m[0]*m[5]*m[10] - m[0]*m[6]*m[9] - m[4]*m[1]*m[10] +
            m[4]*m[2]*m[9] + m[8]*m[1]*m[6] - m[8]*m[2]*m[5];
  float det = m[0]*inv[0] + m[1]*inv[4] + m[2]*inv[8] + m[3]*inv[12];
  det = 1.0f / det;
#pragma unroll
  for (int i = 0; i < 16; i++) invOut[i] = inv[i] * det;
}

// ---------------- splat kernel ----------------
// grid: 2048 blocks of 256 threads; 256 blocks per (b,v) image.
// out layout: (BV, 65, N): channels 0..63 = acc, channel 64 = zsum.
// wsum: (BV, N) in workspace.
__global__ __launch_bounds__(256) void splat_kernel(
    const float* __restrict__ feats, const float* __restrict__ depths,
    const float* __restrict__ Kmat, const float* __restrict__ srcinv,
    const float* __restrict__ dstRT, float* __restrict__ out,
    float* __restrict__ wsum) {
  const int bv = blockIdx.x >> 8;            // 256 blocks per bv
  const int n = ((blockIdx.x & 255) << 8) | threadIdx.x;
  const int b = bv >> 2;                     // V = 4

  __shared__ float T[16];
  if (threadIdx.x == 0) {
    // T = K[b] @ dstRT[b] @ srcinv[b,v] @ Kinv[b]
    float Kinv[16], M1[16], M2[16];
    mat4_inv(Kmat + b * 16, Kinv);
    mat4_mul(srcinv + bv * 16, Kinv, M1);
    mat4_mul(dstRT + b * 16, M1, M2);
    mat4_mul(Kmat + b * 16, M2, T);
  }
  __syncthreads();

  const float d = depths[(size_t)bv * Nn + n];
  const float gx = (float)(n & (Wd - 1));
  const float gy = (float)(n >> 8);

  // xyp = d * (T @ (gx,gy,1,0)) + T[:,3]
  const float p0 = (T[0] * gx + T[1] * gy + T[2]) * d + T[3];
  const float p1 = (T[4] * gx + T[5] * gy + T[6]) * d + T[7];
  const float p2 = (T[8] * gx + T[9] * gy + T[10]) * d + T[11];

  const float z = p2;
  const float ze = z + EPSf;
  const float x = p0 / ze;
  const float y = p1 / ze;
  const float zi = 1.0f / ze;
  const float px0 = rintf(x);   // round-half-even, matches jnp.round
  const float py0 = rintf(y);
  const bool zok = (z > EPSf);

  // cache this pixel's feature vector in registers
  float f[Cc];
  const float* fp = feats + (size_t)bv * Cc * Nn + n;
#pragma unroll
  for (int c = 0; c < Cc; c++) f[c] = fp[(size_t)c * Nn];

  float* outbv = out + (size_t)bv * 65 * Nn;
  float* wbv = wsum + (size_t)bv * Nn;

#pragma unroll
  for (int dy = -2; dy <= 2; dy++) {
#pragma unroll
    for (int dx = -2; dx <= 2; dx++) {
      const float px = px0 + (float)dx;
      const float py = py0 + (float)dy;
      const float ddx = px - x;
      const float ddy = py - y;
      const float dist = sqrtf(ddx * ddx + ddy * ddy + EPSf);
      float w = fmaxf(0.0f, 1.0f - dist * 0.5f);  // RADIUS = 2
      const bool valid = zok && (px >= 0.0f) && (px < (float)Wd) &&
                         (py >= 0.0f) && (py < (float)Hd);
      w = valid ? w * zi : 0.0f;
      if (w > 0.0f) {
        const int idx = (int)py * Wd + (int)px;  // px,py >= 0 and integral here
        atomicAdd(wbv + idx, w);
        atomicAdd(outbv + (size_t)Cc * Nn + idx, w * z);  // zsum channel
#pragma unroll
        for (int c = 0; c < Cc; c++)
          atomicAdd(outbv + (size_t)c * Nn + idx, w * f[c]);
      }
    }
  }
}

// ---------------- normalize kernel ----------------
// out[t] /= (wsum + EPS) for all 65 channels (acc and zsum share denominator).
__global__ __launch_bounds__(256) void norm_kernel(float* __restrict__ out,
                                                   const float* __restrict__ wsum) {
  const int t = blockIdx.x * 256 + threadIdx.x;  // < BV*65*N = 34,078,720
  const int n = t & 0xFFFF;
  const int bvc = t >> 16;     // bv*65 + c
  const int bv = bvc / 65;
  const float wv = wsum[(size_t)bv * Nn + n];
  out[t] = out[t] / (wv + EPSf);
}

extern "C" void kernel_launch(void* const* d_in, const int* in_sizes, int n_in,
                              void* d_out, int out_size, void* d_ws, size_t ws_size,
                              hipStream_t stream) {
  const float* feats  = (const float*)d_in[0];  // (B,V,C,H,W)
  const float* depths = (const float*)d_in[1];  // (B,V,1,H,W)
  const float* Kmat   = (const float*)d_in[2];  // (B,4,4)
  const float* srcinv = (const float*)d_in[4];  // (B,V,4,4)
  const float* dstRT  = (const float*)d_in[5];  // (B,1,4,4)
  float* out  = (float*)d_out;                  // (B,V,65,H,W)
  float* wsum = (float*)d_ws;                   // (BV,N) floats = 2 MB

  // zero accumulators (harness poisons d_out/d_ws with 0xAA)
  hipMemsetAsync(out, 0, (size_t)out_size * sizeof(float), stream);
  hipMemsetAsync(wsum, 0, (size_t)BVn * Nn * sizeof(float), stream);

  splat_kernel<<<dim3(BVn * (Nn / 256)), dim3(256), 0, stream>>>(
      feats, depths, Kmat, srcinv, dstRT, out, wsum);

  const int total = BVn * 65 * Nn;
  norm_kernel<<<dim3(total / 256), dim3(256), 0, stream>>>(out, wsum);
}

// Round 2
// 612.886 us; speedup vs baseline: 15.0164x; 15.0164x over previous
//
#include <hip/hip_runtime.h>

#define Wd 256
#define Hd 256
#define Nn 65536   // H*W
#define Cc 64
#define Vv 4
#define Bb 2
#define BVn 8
#define EPSf 1e-8f

// ---- workspace layout (bytes) ----
#define OFF_COUNT   ((size_t)0)            // u32[524288]  2 MiB
#define OFF_OFFS    ((size_t)2  << 20)     // u32[524288]  2 MiB
#define OFF_CURS    ((size_t)4  << 20)     // u32[524288]  2 MiB
#define OFF_ROWSUM  ((size_t)6  << 20)     // u32[2048]
#define OFF_ROWBASE (((size_t)6 << 20) + 65536)
#define OFF_STAGE1  ((size_t)8  << 20)     // float4[524288] 8 MiB
#define OFF_BINNED  ((size_t)16 << 20)     // float4[524288] 8 MiB
#define OFF_FT      ((size_t)24 << 20)     // float[8*65536*64] 128 MiB
#define FT_BYTES    ((size_t)BVn * Nn * Cc * 4)
#define NEED_FULL   (OFF_FT + FT_BYTES)
#define NEED_MID    OFF_FT

// ---------------- small matrix helpers ----------------
__device__ inline void mat4_mul(const float* A, const float* B, float* C) {
#pragma unroll
  for (int i = 0; i < 4; i++)
#pragma unroll
    for (int j = 0; j < 4; j++) {
      float s = 0.f;
#pragma unroll
      for (int k = 0; k < 4; k++) s += A[i * 4 + k] * B[k * 4 + j];
      C[i * 4 + j] = s;
    }
}

__device__ inline void mat4_inv(const float* m, float* invOut) {
  float inv[16];
  inv[0] = m[5]*m[10]*m[15] - m[5]*m[11]*m[14] - m[9]*m[6]*m[15] +
           m[9]*m[7]*m[14] + m[13]*m[6]*m[11] - m[13]*m[7]*m[10];
  inv[4] = -m[4]*m[10]*m[15] + m[4]*m[11]*m[14] + m[8]*m[6]*m[15] -
           m[8]*m[7]*m[14] - m[12]*m[6]*m[11] + m[12]*m[7]*m[10];
  inv[8] = m[4]*m[9]*m[15] - m[4]*m[11]*m[13] - m[8]*m[5]*m[15] +
           m[8]*m[7]*m[13] + m[12]*m[5]*m[11] - m[12]*m[7]*m[9];
  inv[12] = -m[4]*m[9]*m[14] + m[4]*m[10]*m[13] + m[8]*m[5]*m[14] -
            m[8]*m[6]*m[13] - m[12]*m[5]*m[10] + m[12]*m[6]*m[9];
  inv[1] = -m[1]*m[10]*m[15] + m[1]*m[11]*m[14] + m[9]*m[2]*m[15] -
           m[9]*m[3]*m[14] - m[13]*m[2]*m[11] + m[13]*m[3]*m[10];
  inv[5] = m[0]*m[10]*m[15] - m[0]*m[11]*m[14] - m[8]*m[2]*m[15] +
           m[8]*m[3]*m[14] + m[12]*m[2]*m[11] - m[12]*m[3]*m[10];
  inv[9] = -m[0]*m[9]*m[15] + m[0]*m[11]*m[13] + m[8]*m[1]*m[15] -
           m[8]*m[3]*m[13] - m[12]*m[1]*m[11] + m[12]*m[3]*m[9];
  inv[13] = m[0]*m[9]*m[14] - m[0]*m[10]*m[13] - m[8]*m[1]*m[14] +
            m[8]*m[2]*m[13] + m[12]*m[1]*m[10] - m[12]*m[2]*m[9];
  inv[2] = m[1]*m[6]*m[15] - m[1]*m[7]*m[14] - m[5]*m[2]*m[15] +
           m[5]*m[3]*m[14] + m[13]*m[2]*m[7] - m[13]*m[3]*m[6];
  inv[6] = -m[0]*m[6]*m[15] + m[0]*m[7]*m[14] + m[4]*m[2]*m[15] -
           m[4]*m[3]*m[14] - m[12]*m[2]*m[7] + m[12]*m[3]*m[6];
  inv[10] = m[0]*m[5]*m[15] - m[0]*m[7]*m[13] - m[4]*m[1]*m[15] +
            m[4]*m[3]*m[13] + m[12]*m[1]*m[7] - m[12]*m[3]*m[5];
  inv[14] = -m[0]*m[5]*m[14] + m[0]*m[6]*m[13] + m[4]*m[1]*m[14] -
            m[4]*m[2]*m[13] - m[12]*m[1]*m[6] + m[12]*m[2]*m[5];
  inv[3] = -m[1]*m[6]*m[11] + m[1]*m[7]*m[10] + m[5]*m[2]*m[11] -
           m[5]*m[3]*m[10] - m[9]*m[2]*m[7] + m[9]*m[3]*m[6];
  inv[7] = m[0]*m[6]*m[11] - m[0]*m[7]*m[10] - m[4]*m[2]*m[11] +
           m[4]*m[3]*m[10] + m[8]*m[2]*m[7] - m[8]*m[3]*m[6];
  inv[11] = -m[0]*m[5]*m[11] + m[0]*m[7]*m[9] + m[4]*m[1]*m[11] -
            m[4]*m[3]*m[9] - m[8]*m[1]*m[7] + m[8]*m[3]*m[5];
  inv[15] = m[0]*m[5]*m[10] - m[0]*m[6]*m[9] - m[4]*m[1]*m[10] +
            m[4]*m[2]*m[9] + m[8]*m[1]*m[6] - m[8]*m[2]*m[5];
  float det = m[0]*inv[0] + m[1]*inv[4] + m[2]*inv[8] + m[3]*inv[12];
  det = 1.0f / det;
#pragma unroll
  for (int i = 0; i < 16; i++) invOut[i] = inv[i] * det;
}

__device__ inline void compute_T(const float* Kmat, const float* srcinv,
                                 const float* dstRT, int b, int bv, float* T) {
  float Kinv[16], M1[16], M2[16];
  mat4_inv(Kmat + b * 16, Kinv);
  mat4_mul(srcinv + bv * 16, Kinv, M1);
  mat4_mul(dstRT + b * 16, M1, M2);
  mat4_mul(Kmat + b * 16, M2, T);
}

// ---------------- K0: transpose feats (BV,C,N) -> featsT (BV,N,C) ----------
__global__ __launch_bounds__(256) void transpose_kernel(
    const float* __restrict__ feats, float* __restrict__ featsT) {
  __shared__ float lds[Cc][65];  // 64 x 65 floats, pad avoids bank conflicts
  const int bv = blockIdx.x >> 10;
  const int n0 = (blockIdx.x & 1023) << 6;  // 64 pixels per block
  const int t = threadIdx.x;

  const float* src = feats + (size_t)bv * Cc * Nn;
  {
    const int c_l = t >> 6;   // 0..3
    const int n_l = t & 63;
#pragma unroll
    for (int i = 0; i < 16; i++) {
      const int c = c_l * 16 + i;
      lds[c][n_l] = src[(size_t)c * Nn + n0 + n_l];
    }
  }
  __syncthreads();
  {
    const int c_l = t & 63;
    const int n_b = t >> 6;   // 0..3
    float* dst = featsT + ((size_t)bv * Nn + n0) * Cc;
#pragma unroll
    for (int i = 0; i < 16; i++) {
      const int n = n_b * 16 + i;
      dst[(size_t)n * Cc + c_l] = lds[c_l][n];
    }
  }
}

// ---------------- K1: project, count, stage ----------------
__global__ __launch_bounds__(256) void project_count_kernel(
    const float* __restrict__ depths, const float* __restrict__ Kmat,
    const float* __restrict__ srcinv, const float* __restrict__ dstRT,
    unsigned int* __restrict__ counts, float4* __restrict__ stage1) {
  const int bv = blockIdx.x >> 8;
  const int n = ((blockIdx.x & 255) << 8) | threadIdx.x;
  const int b = bv >> 2;

  __shared__ float T[16];
  if (threadIdx.x == 0) compute_T(Kmat, srcinv, dstRT, b, bv, T);
  __syncthreads();

  const float d = depths[(size_t)bv * Nn + n];
  const float gx = (float)(n & (Wd - 1));
  const float gy = (float)(n >> 8);

  const float p0 = (T[0] * gx + T[1] * gy + T[2]) * d + T[3];
  const float p1 = (T[4] * gx + T[5] * gy + T[6]) * d + T[7];
  const float z  = (T[8] * gx + T[9] * gy + T[10]) * d + T[11];

  const float ze = z + EPSf;
  const float x = p0 / ze;
  const float y = p1 / ze;
  const float px0 = rintf(x);
  const float py0 = rintf(y);

  int bin = -1;
  if (z > EPSf && px0 >= -2.0f && px0 <= (float)(Wd + 1) &&
      py0 >= -2.0f && py0 <= (float)(Hd + 1)) {
    const int bx = min(max((int)px0, 0), Wd - 1);
    const int by = min(max((int)py0, 0), Hd - 1);
    bin = (bv << 16) | (by << 8) | bx;
    atomicAdd(&counts[bin], 1u);
  }
  float4 rec;
  rec.x = x; rec.y = y; rec.z = z; rec.w = __int_as_float(bin);
  stage1[(size_t)bv * Nn + n] = rec;
}

// ---------------- K2a: per-row sums (2048 rows x 256 bins) ----------------
__global__ __launch_bounds__(256) void row_sum_kernel(
    const unsigned int* __restrict__ counts, unsigned int* __restrict__ rowsum) {
  const int r = blockIdx.x * 256 + threadIdx.x;  // 0..2047
  unsigned int s = 0;
  const unsigned int* c = counts + (size_t)r * 256;
  for (int i = 0; i < 256; i++) s += c[i];
  rowsum[r] = s;
}

// ---------------- K2b: exclusive scan of 2048 row sums (one block) --------
__global__ __launch_bounds__(256) void scan_rows_kernel(
    const unsigned int* __restrict__ rowsum, unsigned int* __restrict__ rowbase) {
  __shared__ unsigned int part[256];
  const int t = threadIdx.x;
  unsigned int loc[8];
  unsigned int run = 0;
#pragma unroll
  for (int i = 0; i < 8; i++) {
    loc[i] = run;
    run += rowsum[t * 8 + i];
  }
  part[t] = run;
  __syncthreads();
  for (int off = 1; off < 256; off <<= 1) {
    unsigned int x = part[t];
    unsigned int y = (t >= off) ? part[t - off] : 0u;
    __syncthreads();
    part[t] = x + y;
    __syncthreads();
  }
  const unsigned int base = (t == 0) ? 0u : part[t - 1];
#pragma unroll
  for (int i = 0; i < 8; i++) rowbase[t * 8 + i] = base + loc[i];
}

// ---------------- K2c: per-bin offsets + cursors ----------------
__global__ __launch_bounds__(256) void bin_offsets_kernel(
    const unsigned int* __restrict__ counts, const unsigned int* __restrict__ rowbase,
    unsigned int* __restrict__ offs, unsigned int* __restrict__ curs) {
  const int r = blockIdx.x * 256 + threadIdx.x;  // 0..2047
  unsigned int run = rowbase[r];
  const size_t base = (size_t)r * 256;
  for (int i = 0; i < 256; i++) {
    const unsigned int c = counts[base + i];
    offs[base + i] = run;
    curs[base + i] = run;
    run += c;
  }
}

// ---------------- K3: fill binned records ----------------
__global__ __launch_bounds__(256) void fill_kernel(
    const float4* __restrict__ stage1, unsigned int* __restrict__ curs,
    float4* __restrict__ binned) {
  const int g = blockIdx.x * 256 + threadIdx.x;  // 0..524287
  float4 rec = stage1[g];
  const int bin = __float_as_int(rec.w);
  if (bin >= 0) {
    const unsigned int slot = atomicAdd(&curs[bin], 1u);
    rec.w = __int_as_float(g & (Nn - 1));  // pixel index within image
    binned[slot] = rec;
  }
}

// ---------------- K4: gather ----------------
template <bool TRANS>
__global__ __launch_bounds__(256) void gather_kernel(
    const float* __restrict__ featsAny,  // TRANS ? featsT (BV,N,C) : feats (BV,C,N)
    const unsigned int* __restrict__ offs, const unsigned int* __restrict__ curs,
    const float4* __restrict__ binned, float* __restrict__ out) {
  const int bv = blockIdx.x >> 8;
  const int vrow = blockIdx.x & 255;
  const int u = threadIdx.x;

  float acc[Cc];
#pragma unroll
  for (int c = 0; c < Cc; c++) acc[c] = 0.f;
  float wsum = 0.f, wz = 0.f;

  const float uf = (float)u, vf = (float)vrow;
  const int by_lo = max(0, vrow - 2), by_hi = min(Hd - 1, vrow + 2);
  const int bx_lo = max(0, u - 2), bx_hi = min(Wd - 1, u + 2);

  for (int by = by_lo; by <= by_hi; by++) {
    const int rowb = (bv << 16) | (by << 8);
    // bins rowb+bx_lo .. rowb+bx_hi are contiguous in record space
    const unsigned int s = offs[rowb + bx_lo];
    const unsigned int e = curs[rowb + bx_hi];
    for (unsigned int r = s; r < e; r++) {
      const float4 rec = binned[r];
      const float ddx = uf - rec.x;
      const float ddy = vf - rec.y;
      const float dist = sqrtf(ddx * ddx + ddy * ddy + EPSf);
      float w = 1.0f - dist * 0.5f;  // RADIUS = 2
      if (w > 0.f) {
        w *= 1.0f / (rec.z + EPSf);
        wsum += w;
        wz += w * rec.z;
        const int n = __float_as_int(rec.w);
        if (TRANS) {
          const float4* fs = reinterpret_cast<const float4*>(
              featsAny + ((size_t)(bv << 16 | n)) * Cc);
#pragma unroll
          for (int i = 0; i < 16; i++) {
            const float4 fv = fs[i];
            acc[4 * i + 0] += w * fv.x;
            acc[4 * i + 1] += w * fv.y;
            acc[4 * i + 2] += w * fv.z;
            acc[4 * i + 3] += w * fv.w;
          }
        } else {
          const float* fp = featsAny + ((size_t)bv * Cc << 16) + n;
#pragma unroll
          for (int c = 0; c < Cc; c++) acc[c] += w * fp[(size_t)c << 16];
        }
      }
    }
  }

  const float inv = 1.0f / (wsum + EPSf);
  const int dest = (vrow << 8) | u;
  float* ob = out + (((size_t)bv * 65) << 16) + dest;
#pragma unroll
  for (int c = 0; c < Cc; c++) ob[(size_t)c << 16] = acc[c] * inv;
  ob[(size_t)Cc << 16] = wz * inv;
}

// ---------------- fallback: round-1 atomic splat ----------------
__global__ __launch_bounds__(256) void splat_kernel(
    const float* __restrict__ feats, const float* __restrict__ depths,
    const float* __restrict__ Kmat, const float* __restrict__ srcinv,
    const float* __restrict__ dstRT, float* __restrict__ out,
    float* __restrict__ wsum) {
  const int bv = blockIdx.x >> 8;
  const int n = ((blockIdx.x & 255) << 8) | threadIdx.x;
  const int b = bv >> 2;

  __shared__ float T[16];
  if (threadIdx.x == 0) compute_T(Kmat, srcinv, dstRT, b, bv, T);
  __syncthreads();

  const float d = depths[(size_t)bv * Nn + n];
  const float gx = (float)(n & (Wd - 1));
  const float gy = (float)(n >> 8);
  const float p0 = (T[0] * gx + T[1] * gy + T[2]) * d + T[3];
  const float p1 = (T[4] * gx + T[5] * gy + T[6]) * d + T[7];
  const float z  = (T[8] * gx + T[9] * gy + T[10]) * d + T[11];
  const float ze = z + EPSf;
  const float x = p0 / ze, y = p1 / ze;
  const float zi = 1.0f / ze;
  const float px0 = rintf(x), py0 = rintf(y);
  const bool zok = (z > EPSf);

  float f[Cc];
  const float* fp = feats + (size_t)bv * Cc * Nn + n;
#pragma unroll
  for (int c = 0; c < Cc; c++) f[c] = fp[(size_t)c * Nn];

  float* outbv = out + (size_t)bv * 65 * Nn;
  float* wbv = wsum + (size_t)bv * Nn;
#pragma unroll
  for (int dy = -2; dy <= 2; dy++) {
#pragma unroll
    for (int dx = -2; dx <= 2; dx++) {
      const float px = px0 + (float)dx;
      const float py = py0 + (float)dy;
      const float ddx = px - x, ddy = py - y;
      const float dist = sqrtf(ddx * ddx + ddy * ddy + EPSf);
      float w = fmaxf(0.0f, 1.0f - dist * 0.5f);
      const bool valid = zok && (px >= 0.0f) && (px < (float)Wd) &&
                         (py >= 0.0f) && (py < (float)Hd);
      w = valid ? w * zi : 0.0f;
      if (w > 0.0f) {
        const int idx = (int)py * Wd + (int)px;
        atomicAdd(wbv + idx, w);
        atomicAdd(outbv + (size_t)Cc * Nn + idx, w * z);
#pragma unroll
        for (int c = 0; c < Cc; c++)
          atomicAdd(outbv + (size_t)c * Nn + idx, w * f[c]);
      }
    }
  }
}

__global__ __launch_bounds__(256) void norm_kernel(float* __restrict__ out,
                                                   const float* __restrict__ wsum) {
  const int t = blockIdx.x * 256 + threadIdx.x;
  const int n = t & 0xFFFF;
  const int bvc = t >> 16;
  const int bv = bvc / 65;
  const float wv = wsum[(size_t)bv * Nn + n];
  out[t] = out[t] / (wv + EPSf);
}

extern "C" void kernel_launch(void* const* d_in, const int* in_sizes, int n_in,
                              void* d_out, int out_size, void* d_ws, size_t ws_size,
                              hipStream_t stream) {
  const float* feats  = (const float*)d_in[0];
  const float* depths = (const float*)d_in[1];
  const float* Kmat   = (const float*)d_in[2];
  const float* srcinv = (const float*)d_in[4];
  const float* dstRT  = (const float*)d_in[5];
  float* out = (float*)d_out;
  char* ws = (char*)d_ws;

  if (ws_size >= NEED_MID) {
    unsigned int* counts = (unsigned int*)(ws + OFF_COUNT);
    unsigned int* offs   = (unsigned int*)(ws + OFF_OFFS);
    unsigned int* curs   = (unsigned int*)(ws + OFF_CURS);
    unsigned int* rowsum = (unsigned int*)(ws + OFF_ROWSUM);
    unsigned int* rowbase= (unsigned int*)(ws + OFF_ROWBASE);
    float4* stage1 = (float4*)(ws + OFF_STAGE1);
    float4* binned = (float4*)(ws + OFF_BINNED);
    float* featsT  = (float*)(ws + OFF_FT);

    hipMemsetAsync(counts, 0, (size_t)BVn * Nn * sizeof(unsigned int), stream);

    const bool trans = (ws_size >= NEED_FULL);
    if (trans)
      transpose_kernel<<<dim3(BVn * (Nn / 64)), dim3(256), 0, stream>>>(feats, featsT);

    project_count_kernel<<<dim3(BVn * (Nn / 256)), dim3(256), 0, stream>>>(
        depths, Kmat, srcinv, dstRT, counts, stage1);
    row_sum_kernel<<<dim3(8), dim3(256), 0, stream>>>(counts, rowsum);
    scan_rows_kernel<<<dim3(1), dim3(256), 0, stream>>>(rowsum, rowbase);
    bin_offsets_kernel<<<dim3(8), dim3(256), 0, stream>>>(counts, rowbase, offs, curs);
    fill_kernel<<<dim3(BVn * Nn / 256), dim3(256), 0, stream>>>(stage1, curs, binned);

    if (trans)
      gather_kernel<true><<<dim3(BVn * Hd), dim3(256), 0, stream>>>(
          featsT, offs, curs, binned, out);
    else
      gather_kernel<false><<<dim3(BVn * Hd), dim3(256), 0, stream>>>(
          feats, offs, curs, binned, out);
  } else {
    // atomic fallback (round-1 path)
    float* wsum = (float*)ws;  // (BV,N) = 2 MiB
    hipMemsetAsync(out, 0, (size_t)out_size * sizeof(float), stream);
    hipMemsetAsync(wsum, 0, (size_t)BVn * Nn * sizeof(float), stream);
    splat_kernel<<<dim3(BVn * (Nn / 256)), dim3(256), 0, stream>>>(
        feats, depths, Kmat, srcinv, dstRT, out, wsum);
    norm_kernel<<<dim3(BVn * 65 * Nn / 256), dim3(256), 0, stream>>>(out, wsum);
  }
}